// Round 1
// baseline (449.538 us; speedup 1.0000x reference)
//
#include <hip/hip_runtime.h>
#include <stdint.h>

// ---------------------------------------------------------------------------
// MultiHeadAttnCoupling: B=4 N=128 -> BN=512 rows
//   Q = z(512x256) @ Wq(256x32768) + bq
//   K = x(512x512) @ Wk(512x32768) + bk ; V likewise
//   per (bn, h in 0..7): S = Q64x64 K^T /8 ; P=softmax(S); O = P V
//   out = O(512x32768) @ Wo(32768x512) + bo   (fp32 out)
//
// ws layout (bytes), peak 184,549,376:
//   WqT  @ 0          (16,777,216)  [dead after gemm Q]   } Ob @ 0 (33,554,432)
//   WkT  @ 16,777,216 (33,554,432)  [dead after gemm K]   }   overwrites both
//   WvT  @ 50,331,648 (33,554,432)  [dead after gemm V] -> WoT @ same (33,554,432)
//   Qb   @ 83,886,080  Kb @ 117,440,512  Vb @ 150,994,944 (bf16, 33.5MB each)
// ---------------------------------------------------------------------------

typedef __attribute__((ext_vector_type(8))) short short8;
typedef __attribute__((ext_vector_type(4))) float floatx4;

__device__ __forceinline__ unsigned short f2bf(float f) {
  union { float f; unsigned int u; } v; v.f = f;
  unsigned int u = v.u + 0x7FFFu + ((v.u >> 16) & 1u);   // round-to-nearest-even
  return (unsigned short)(u >> 16);
}

#define MFMA16(a, b, c) __builtin_amdgcn_mfma_f32_16x16x32_bf16((a), (b), (c), 0, 0, 0)

// ---------------- weight transpose+convert: W[K][N] f32 -> WT[N][K] bf16 ----
__global__ __launch_bounds__(256) void transpose_w(const float* __restrict__ W,
                                                   unsigned short* __restrict__ WT,
                                                   int K, int N) {
  __shared__ __align__(16) unsigned short T[64 * 72];  // 72 pad: b128-aligned rows
  const int tid = threadIdx.x;
  const int n0 = blockIdx.x * 64, k0 = blockIdx.y * 64;
#pragma unroll
  for (int i = 0; i < 4; ++i) {
    int e = tid + (i << 8);            // [0,1024): 64 k-rows x 16 float4
    int r = e >> 4, c = (e & 15) << 2;
    float4 w = *(const float4*)(W + (size_t)(k0 + r) * N + n0 + c);
    T[(c + 0) * 72 + r] = f2bf(w.x);
    T[(c + 1) * 72 + r] = f2bf(w.y);
    T[(c + 2) * 72 + r] = f2bf(w.z);
    T[(c + 3) * 72 + r] = f2bf(w.w);
  }
  __syncthreads();
#pragma unroll
  for (int i = 0; i < 2; ++i) {
    int e = tid + (i << 8);            // [0,512): 64 n-rows x 8 x 16B
    int n = e >> 3, kc = e & 7;
    uint4 vv = *(const uint4*)(&T[n * 72 + kc * 8]);   // byte off = n*144+kc*16, 16B aligned
    *(uint4*)(WT + (size_t)(n0 + n) * K + k0 + kc * 8) = vv;
  }
}

// ---------------- QKV gemm: C_bf16[512][32768] = A_f32[512][Ka] * BT^T + bias
__global__ __launch_bounds__(256) void gemm_qkv(const float* __restrict__ A,
                                                const unsigned short* __restrict__ BT,
                                                const float* __restrict__ bias,
                                                unsigned short* __restrict__ C, int Ka) {
  __shared__ __align__(16) unsigned short As[128 * 32];
  __shared__ __align__(16) unsigned short Bs[128 * 32];
  const int tid = threadIdx.x;
  const int lane = tid & 63, wid = tid >> 6;
  const int quad = lane >> 4, l15 = lane & 15;
  const int wm = wid >> 1, wn = wid & 1;
  const int m0 = blockIdx.y * 128, n0 = blockIdx.x * 128;
  floatx4 acc[4][4] = {};
  for (int k0 = 0; k0 < Ka; k0 += 32) {
    // B tile: bf16 WT rows, async direct-to-LDS, 16B/lane
#pragma unroll
    for (int i = 0; i < 2; ++i) {
      int e = tid + (i << 8);
      int n = e >> 2, kq = e & 3;
      const unsigned short* src = BT + (size_t)(n0 + n) * Ka + k0 + (kq << 3);
      __builtin_amdgcn_global_load_lds(
          (const __attribute__((address_space(1))) unsigned int*)src,
          (__attribute__((address_space(3))) unsigned int*)(&Bs[e << 3]), 16, 0, 0);
    }
    // A tile: fp32 -> bf16 in VGPRs (A is tiny, L2-resident)
#pragma unroll
    for (int i = 0; i < 2; ++i) {
      int e = tid + (i << 8);
      int r = e >> 2, kq = e & 3;
      const float* src = A + (size_t)(m0 + r) * Ka + k0 + (kq << 3);
      float4 f0 = *(const float4*)src;
      float4 f1 = *(const float4*)(src + 4);
      uint4 p;
      p.x = f2bf(f0.x) | ((unsigned)f2bf(f0.y) << 16);
      p.y = f2bf(f0.z) | ((unsigned)f2bf(f0.w) << 16);
      p.z = f2bf(f1.x) | ((unsigned)f2bf(f1.y) << 16);
      p.w = f2bf(f1.z) | ((unsigned)f2bf(f1.w) << 16);
      *(uint4*)(&As[e << 3]) = p;
    }
    __syncthreads();
    short8 aF[4], bF[4];
#pragma unroll
    for (int mi = 0; mi < 4; ++mi)
      aF[mi] = *(const short8*)(&As[((wm * 64 + mi * 16 + l15) << 5) + (quad << 3)]);
#pragma unroll
    for (int ni = 0; ni < 4; ++ni)
      bF[ni] = *(const short8*)(&Bs[((wn * 64 + ni * 16 + l15) << 5) + (quad << 3)]);
#pragma unroll
    for (int mi = 0; mi < 4; ++mi)
#pragma unroll
      for (int ni = 0; ni < 4; ++ni)
        acc[mi][ni] = MFMA16(aF[mi], bF[ni], acc[mi][ni]);
    __syncthreads();
  }
  // epilogue: +bias, bf16 store (C/D layout: col=lane&15, row=quad*4+reg)
#pragma unroll
  for (int ni = 0; ni < 4; ++ni) {
    int col = n0 + wn * 64 + ni * 16 + l15;
    float bv = bias[col];
#pragma unroll
    for (int mi = 0; mi < 4; ++mi) {
      int row = m0 + wm * 64 + mi * 16 + (quad << 2);
#pragma unroll
      for (int r = 0; r < 4; ++r)
        C[(size_t)(row + r) * 32768 + col] = f2bf(acc[mi][ni][r] + bv);
    }
  }
}

// ---------------- attention: one block per (bn, h), 64x64 tiles ------------
__global__ __launch_bounds__(256) void attn64(const unsigned short* __restrict__ Qb,
                                              const unsigned short* __restrict__ Kb,
                                              const unsigned short* __restrict__ Vb,
                                              unsigned short* __restrict__ Ob) {
  __shared__ __align__(16) unsigned short Qs[64 * 72];
  __shared__ __align__(16) unsigned short Ks[64 * 72];
  __shared__ __align__(16) unsigned short VT[64 * 72];
  __shared__ __align__(16) unsigned short Ps[64 * 72];
  const int tid = threadIdx.x;
  const int bn = blockIdx.x >> 3, h = blockIdx.x & 7;
  const size_t base = (size_t)bn * 32768 + (size_t)h * 4096;
  const unsigned short* q = Qb + base;
  const unsigned short* k = Kb + base;
  const unsigned short* v = Vb + base;
#pragma unroll
  for (int i = 0; i < 2; ++i) {
    int e = tid + (i << 8);           // [0,512)
    int r = e >> 3, dblk = e & 7;
    *(uint4*)(&Qs[r * 72 + dblk * 8]) = *(const uint4*)(q + r * 64 + dblk * 8);
    *(uint4*)(&Ks[r * 72 + dblk * 8]) = *(const uint4*)(k + r * 64 + dblk * 8);
    uint4 vv = *(const uint4*)(v + r * 64 + dblk * 8);
    const unsigned short* pv = (const unsigned short*)&vv;
#pragma unroll
    for (int j = 0; j < 8; ++j)       // transpose V: VT[d][kk]
      VT[(dblk * 8 + j) * 72 + r] = pv[j];
  }
  __syncthreads();
  const int lane = tid & 63, wid = tid >> 6;
  const int quad = lane >> 4, l15 = lane & 15;
  const int qs = wid << 4;            // this wave's 16 q-rows
  short8 aq0 = *(const short8*)(&Qs[(qs + l15) * 72 + quad * 8]);
  short8 aq1 = *(const short8*)(&Qs[(qs + l15) * 72 + 32 + quad * 8]);
  floatx4 s[4] = {};
#pragma unroll
  for (int ni = 0; ni < 4; ++ni) {
    short8 b0 = *(const short8*)(&Ks[(ni * 16 + l15) * 72 + quad * 8]);
    short8 b1 = *(const short8*)(&Ks[(ni * 16 + l15) * 72 + 32 + quad * 8]);
    s[ni] = MFMA16(aq0, b0, s[ni]);
    s[ni] = MFMA16(aq1, b1, s[ni]);
  }
  // softmax per row (row = qs + quad*4 + r, spread over the quad's 16 lanes)
#pragma unroll
  for (int r = 0; r < 4; ++r) {
    float e0 = s[0][r] * 0.125f, e1 = s[1][r] * 0.125f;
    float e2 = s[2][r] * 0.125f, e3 = s[3][r] * 0.125f;
    float m = fmaxf(fmaxf(e0, e1), fmaxf(e2, e3));
    m = fmaxf(m, __shfl_xor(m, 1));
    m = fmaxf(m, __shfl_xor(m, 2));
    m = fmaxf(m, __shfl_xor(m, 4));
    m = fmaxf(m, __shfl_xor(m, 8));
    float x0 = __expf(e0 - m), x1 = __expf(e1 - m);
    float x2 = __expf(e2 - m), x3 = __expf(e3 - m);
    float t = x0 + x1 + x2 + x3;
    t += __shfl_xor(t, 1); t += __shfl_xor(t, 2);
    t += __shfl_xor(t, 4); t += __shfl_xor(t, 8);
    float inv = __builtin_amdgcn_rcpf(t);
    int row = qs + (quad << 2) + r;
    Ps[row * 72 +      l15] = f2bf(x0 * inv);
    Ps[row * 72 + 16 + l15] = f2bf(x1 * inv);
    Ps[row * 72 + 32 + l15] = f2bf(x2 * inv);
    Ps[row * 72 + 48 + l15] = f2bf(x3 * inv);
  }
  __syncthreads();   // P strips are wave-local, but be safe
  short8 ap0 = *(const short8*)(&Ps[(qs + l15) * 72 + quad * 8]);
  short8 ap1 = *(const short8*)(&Ps[(qs + l15) * 72 + 32 + quad * 8]);
  floatx4 o[4] = {};
#pragma unroll
  for (int ni = 0; ni < 4; ++ni) {
    short8 b0 = *(const short8*)(&VT[(ni * 16 + l15) * 72 + quad * 8]);
    short8 b1 = *(const short8*)(&VT[(ni * 16 + l15) * 72 + 32 + quad * 8]);
    o[ni] = MFMA16(ap0, b0, o[ni]);
    o[ni] = MFMA16(ap1, b1, o[ni]);
  }
  unsigned short* outp = Ob + base;
#pragma unroll
  for (int ni = 0; ni < 4; ++ni)
#pragma unroll
    for (int r = 0; r < 4; ++r)
      outp[(qs + (quad << 2) + r) * 64 + ni * 16 + l15] = f2bf(o[ni][r]);
}

// ---------------- out gemm: C_f32[512][512] += Ob[512][32768] * WoT^T, split-K
__global__ __launch_bounds__(256) void gemm_out(const unsigned short* __restrict__ A,
                                                const unsigned short* __restrict__ BT,
                                                const float* __restrict__ bias,
                                                float* __restrict__ C) {
  __shared__ __align__(16) unsigned short As[128 * 32];
  __shared__ __align__(16) unsigned short Bs[128 * 32];
  const int tid = threadIdx.x;
  const int lane = tid & 63, wid = tid >> 6;
  const int quad = lane >> 4, l15 = lane & 15;
  const int wm = wid >> 1, wn = wid & 1;
  const int m0 = blockIdx.y * 128, n0 = blockIdx.x * 128;
  const int kbase = blockIdx.z * 2048;
  floatx4 acc[4][4] = {};
  for (int k0 = kbase; k0 < kbase + 2048; k0 += 32) {
#pragma unroll
    for (int i = 0; i < 2; ++i) {
      int e = tid + (i << 8);
      int r = e >> 2, kq = e & 3;
      __builtin_amdgcn_global_load_lds(
          (const __attribute__((address_space(1))) unsigned int*)(A + (size_t)(m0 + r) * 32768 + k0 + (kq << 3)),
          (__attribute__((address_space(3))) unsigned int*)(&As[e << 3]), 16, 0, 0);
      __builtin_amdgcn_global_load_lds(
          (const __attribute__((address_space(1))) unsigned int*)(BT + (size_t)(n0 + r) * 32768 + k0 + (kq << 3)),
          (__attribute__((address_space(3))) unsigned int*)(&Bs[e << 3]), 16, 0, 0);
    }
    __syncthreads();
    short8 aF[4], bF[4];
#pragma unroll
    for (int mi = 0; mi < 4; ++mi)
      aF[mi] = *(const short8*)(&As[((wm * 64 + mi * 16 + l15) << 5) + (quad << 3)]);
#pragma unroll
    for (int ni = 0; ni < 4; ++ni)
      bF[ni] = *(const short8*)(&Bs[((wn * 64 + ni * 16 + l15) << 5) + (quad << 3)]);
#pragma unroll
    for (int mi = 0; mi < 4; ++mi)
#pragma unroll
      for (int ni = 0; ni < 4; ++ni)
        acc[mi][ni] = MFMA16(aF[mi], bF[ni], acc[mi][ni]);
    __syncthreads();
  }
#pragma unroll
  for (int ni = 0; ni < 4; ++ni) {
    int col = n0 + wn * 64 + ni * 16 + l15;
    float bv = (blockIdx.z == 0) ? bias[col] : 0.0f;
#pragma unroll
    for (int mi = 0; mi < 4; ++mi) {
      int row = m0 + wm * 64 + mi * 16 + (quad << 2);
#pragma unroll
      for (int r = 0; r < 4; ++r)
        atomicAdd(&C[(size_t)(row + r) * 512 + col], acc[mi][ni][r] + bv);
    }
  }
}

extern "C" void kernel_launch(void* const* d_in, const int* in_sizes, int n_in,
                              void* d_out, int out_size, void* d_ws, size_t ws_size,
                              hipStream_t stream) {
  const float* x  = (const float*)d_in[0];
  const float* z  = (const float*)d_in[1];
  const float* Wq = (const float*)d_in[2];
  const float* bq = (const float*)d_in[3];
  const float* Wk = (const float*)d_in[4];
  const float* bk = (const float*)d_in[5];
  const float* Wv = (const float*)d_in[6];
  const float* bv = (const float*)d_in[7];
  const float* Wo = (const float*)d_in[8];
  const float* bo = (const float*)d_in[9];
  float* out = (float*)d_out;
  char* ws = (char*)d_ws;

  unsigned short* WqT = (unsigned short*)(ws + 0);
  unsigned short* WkT = (unsigned short*)(ws + 16777216);
  unsigned short* WvT = (unsigned short*)(ws + 50331648);
  unsigned short* Qb  = (unsigned short*)(ws + 83886080);
  unsigned short* Kb  = (unsigned short*)(ws + 117440512);
  unsigned short* Vb  = (unsigned short*)(ws + 150994944);
  unsigned short* Ob  = (unsigned short*)(ws + 0);          // reuse WqT+WkT (dead)
  unsigned short* WoT = (unsigned short*)(ws + 50331648);   // reuse WvT (dead)

  hipMemsetAsync(d_out, 0, (size_t)out_size * sizeof(float), stream);

  transpose_w<<<dim3(512, 4), 256, 0, stream>>>(Wq, WqT, 256, 32768);
  transpose_w<<<dim3(512, 8), 256, 0, stream>>>(Wk, WkT, 512, 32768);
  transpose_w<<<dim3(512, 8), 256, 0, stream>>>(Wv, WvT, 512, 32768);

  gemm_qkv<<<dim3(256, 4), 256, 0, stream>>>(z, WqT, bq, Qb, 256);
  gemm_qkv<<<dim3(256, 4), 256, 0, stream>>>(x, WkT, bk, Kb, 512);
  gemm_qkv<<<dim3(256, 4), 256, 0, stream>>>(x, WvT, bv, Vb, 512);

  transpose_w<<<dim3(8, 512), 256, 0, stream>>>(Wo, WoT, 32768, 512);  // after WvT dead

  attn64<<<dim3(4096), 256, 0, stream>>>(Qb, Kb, Vb, Ob);              // Ob over dead WqT/WkT

  gemm_out<<<dim3(4, 4, 16), 256, 0, stream>>>(Ob, WoT, bo, out);
}

// Round 2
// 396.868 us; speedup vs baseline: 1.1327x; 1.1327x over previous
//
#include <hip/hip_runtime.h>
#include <stdint.h>

// ---------------------------------------------------------------------------
// MultiHeadAttnCoupling: B=4 N=128 -> BN=512 rows
//   Q = z(512x256) @ Wq(256x32768) + bq
//   K = x(512x512) @ Wk(512x32768) + bk ; V likewise
//   per (bn, h in 0..7): S = Q64x64 K^T /8 ; P=softmax(S); O = P V
//   out = O(512x32768) @ Wo(32768x512) + bo   (fp32 out)
//
// ws layout (bytes), peak 184,549,376 (same as validated R0):
//   WqT @ 0          (16MB)  } dead after gemm_qkv -> Ob @ 0 (32MB)
//   WkT @ 16,777,216 (32MB)  }
//   WvT @ 50,331,648 (32MB)    dead after gemm_qkv -> WoT @ same (32MB)
//   Qb  @ 83,886,080  Kb @ 117,440,512  Vb @ 150,994,944 (bf16, 32MB each)
// d_out (1MB) doubles as scratch for xb (512KB) + zb (256KB) until the
// memset right before gemm_out.
// ---------------------------------------------------------------------------

typedef __attribute__((ext_vector_type(8))) short short8;
typedef __attribute__((ext_vector_type(4))) float floatx4;

__device__ __forceinline__ unsigned short f2bf(float f) {
  union { float f; unsigned int u; } v; v.f = f;
  unsigned int u = v.u + 0x7FFFu + ((v.u >> 16) & 1u);   // round-to-nearest-even
  return (unsigned short)(u >> 16);
}

#define MFMA16(a, b, c) __builtin_amdgcn_mfma_f32_16x16x32_bf16((a), (b), (c), 0, 0, 0)

// Stage a 128-row x 64-k bf16 tile into LDS via global_load_lds (16B/lane).
// XOR swizzle: logical k-chunk c (16B granule) of row r is stored at slot
// c^(r&7), so fragment ds_read_b128 spreads over all 32 banks.
#define STAGE_TILE(SRC, LD, LDSARR)                                            \
  do {                                                                         \
    _Pragma("unroll") for (int i_ = 0; i_ < 4; ++i_) {                         \
      int e_ = tid + (i_ << 8);                                                \
      int r_ = e_ >> 3;                                                        \
      int c_ = (e_ & 7) ^ (r_ & 7);                                            \
      __builtin_amdgcn_global_load_lds(                                        \
          (const __attribute__((address_space(1))) unsigned int*)((SRC) +      \
              (size_t)r_ * (LD) + (c_ << 3)),                                  \
          (__attribute__((address_space(3))) unsigned int*)(&(LDSARR)[e_ << 3]),\
          16, 0, 0);                                                           \
    }                                                                          \
  } while (0)

// Fragment read: row in [0,128), KS in {0,1}; logical chunk = KS*4+quad,
// stored at (KS*4+quad)^(row&7). Element offset = row*64 + chunk*8.
#define FRAG(LDSARR, ROW, KS)                                                  \
  (*(const short8*)(&(LDSARR)[(((ROW) << 6)) +                                 \
      ((((((KS) << 2) + quad)) ^ ((ROW) & 7)) << 3)]))

// ---------------- x,z fp32 -> bf16 (into d_out scratch) --------------------
__global__ __launch_bounds__(256) void convert_xz(const float* __restrict__ x,
                                                  const float* __restrict__ z,
                                                  unsigned short* __restrict__ xb,
                                                  unsigned short* __restrict__ zb) {
  int idx = (blockIdx.x * 256 + threadIdx.x) * 8;   // 192 blocks * 2048 = 393216
  const float* src;
  unsigned short* dst;
  if (idx < 262144) { src = x + idx; dst = xb + idx; }
  else              { src = z + (idx - 262144); dst = zb + (idx - 262144); }
  float4 f0 = *(const float4*)src;
  float4 f1 = *(const float4*)(src + 4);
  uint4 p;
  p.x = f2bf(f0.x) | ((unsigned)f2bf(f0.y) << 16);
  p.y = f2bf(f0.z) | ((unsigned)f2bf(f0.w) << 16);
  p.z = f2bf(f1.x) | ((unsigned)f2bf(f1.y) << 16);
  p.w = f2bf(f1.z) | ((unsigned)f2bf(f1.w) << 16);
  *(uint4*)dst = p;
}

// ---------------- weight transpose+convert: W[K][N] f32 -> WT[N][K] bf16 ----
__device__ __forceinline__ void transpose_body(const float* __restrict__ W,
                                               unsigned short* __restrict__ WT,
                                               int K, int N) {
  __shared__ __align__(16) unsigned short T[64 * 72];
  const int tid = threadIdx.x;
  const int n0 = blockIdx.x * 64, k0 = blockIdx.y * 64;
#pragma unroll
  for (int i = 0; i < 4; ++i) {
    int e = tid + (i << 8);
    int r = e >> 4, c = (e & 15) << 2;
    float4 w = *(const float4*)(W + (size_t)(k0 + r) * N + n0 + c);
    T[(c + 0) * 72 + r] = f2bf(w.x);
    T[(c + 1) * 72 + r] = f2bf(w.y);
    T[(c + 2) * 72 + r] = f2bf(w.z);
    T[(c + 3) * 72 + r] = f2bf(w.w);
  }
  __syncthreads();
#pragma unroll
  for (int i = 0; i < 2; ++i) {
    int e = tid + (i << 8);
    int n = e >> 3, kc = e & 7;
    uint4 vv = *(const uint4*)(&T[n * 72 + kc * 8]);
    *(uint4*)(WT + (size_t)(n0 + n) * K + k0 + kc * 8) = vv;
  }
}

__global__ __launch_bounds__(256) void transpose_qkv(const float* __restrict__ Wq,
                                                     const float* __restrict__ Wk,
                                                     const float* __restrict__ Wv,
                                                     unsigned short* __restrict__ WqT,
                                                     unsigned short* __restrict__ WkT,
                                                     unsigned short* __restrict__ WvT) {
  const int zsel = blockIdx.z;
  if (zsel == 0) {
    if (blockIdx.y >= 4) return;                 // Wq: K=256 -> only 4 k-blocks
    transpose_body(Wq, WqT, 256, 32768);
  } else if (zsel == 1) {
    transpose_body(Wk, WkT, 512, 32768);
  } else {
    transpose_body(Wv, WvT, 512, 32768);
  }
}

__global__ __launch_bounds__(256) void transpose_wo(const float* __restrict__ W,
                                                    unsigned short* __restrict__ WT) {
  transpose_body(W, WT, 32768, 512);
}

// ---------------- fused QKV gemm: C_bf16 = A_bf16 * BT^T + bias ------------
__global__ __launch_bounds__(256) void gemm_qkv(const unsigned short* __restrict__ xb,
                                                const unsigned short* __restrict__ zb,
                                                const unsigned short* __restrict__ WqT,
                                                const unsigned short* __restrict__ WkT,
                                                const unsigned short* __restrict__ WvT,
                                                const float* __restrict__ bq,
                                                const float* __restrict__ bk,
                                                const float* __restrict__ bv,
                                                unsigned short* __restrict__ Qb,
                                                unsigned short* __restrict__ Kb,
                                                unsigned short* __restrict__ Vb) {
  __shared__ __align__(16) unsigned short As[128 * 64];
  __shared__ __align__(16) unsigned short Bs[128 * 64];
  const int tid = threadIdx.x;
  const int zsel = blockIdx.z;
  const unsigned short* A;
  const unsigned short* BT;
  const float* bias;
  unsigned short* C;
  int Ka;
  if (zsel == 0)      { A = zb; BT = WqT; bias = bq; C = Qb; Ka = 256; }
  else if (zsel == 1) { A = xb; BT = WkT; bias = bk; C = Kb; Ka = 512; }
  else                { A = xb; BT = WvT; bias = bv; C = Vb; Ka = 512; }
  const int lane = tid & 63, wid = tid >> 6;
  const int quad = lane >> 4, l15 = lane & 15;
  const int wm = wid >> 1, wn = wid & 1;
  const int m0 = blockIdx.y * 128, n0 = blockIdx.x * 128;
  floatx4 acc[4][4] = {};
  for (int k0 = 0; k0 < Ka; k0 += 64) {
    STAGE_TILE(A + (size_t)m0 * Ka + k0, Ka, As);
    STAGE_TILE(BT + (size_t)n0 * Ka + k0, Ka, Bs);
    __syncthreads();
#pragma unroll
    for (int ks = 0; ks < 2; ++ks) {
      short8 aF[4], bF[4];
#pragma unroll
      for (int mi = 0; mi < 4; ++mi) aF[mi] = FRAG(As, wm * 64 + mi * 16 + l15, ks);
#pragma unroll
      for (int ni = 0; ni < 4; ++ni) bF[ni] = FRAG(Bs, wn * 64 + ni * 16 + l15, ks);
#pragma unroll
      for (int mi = 0; mi < 4; ++mi)
#pragma unroll
        for (int ni = 0; ni < 4; ++ni)
          acc[mi][ni] = MFMA16(aF[mi], bF[ni], acc[mi][ni]);
    }
    __syncthreads();
  }
  // epilogue: +bias, bf16 store (C/D layout: col=lane&15, row=quad*4+reg)
#pragma unroll
  for (int ni = 0; ni < 4; ++ni) {
    int col = n0 + wn * 64 + ni * 16 + l15;
    float bv2 = bias[col];
#pragma unroll
    for (int mi = 0; mi < 4; ++mi) {
      int row = m0 + wm * 64 + mi * 16 + (quad << 2);
#pragma unroll
      for (int r = 0; r < 4; ++r)
        C[(size_t)(row + r) * 32768 + col] = f2bf(acc[mi][ni][r] + bv2);
    }
  }
}

// ---------------- attention: one block per (bn, h), 64x64 tiles ------------
__global__ __launch_bounds__(256) void attn64(const unsigned short* __restrict__ Qb,
                                              const unsigned short* __restrict__ Kb,
                                              const unsigned short* __restrict__ Vb,
                                              unsigned short* __restrict__ Ob) {
  __shared__ __align__(16) unsigned short Qs[64 * 72];
  __shared__ __align__(16) unsigned short Ks[64 * 72];
  __shared__ __align__(16) unsigned short VT[64 * 72];
  __shared__ __align__(16) unsigned short Ps[64 * 72];
  const int tid = threadIdx.x;
  const int bn = blockIdx.x >> 3, h = blockIdx.x & 7;
  const size_t base = (size_t)bn * 32768 + (size_t)h * 4096;
  const unsigned short* q = Qb + base;
  const unsigned short* k = Kb + base;
  const unsigned short* v = Vb + base;
#pragma unroll
  for (int i = 0; i < 2; ++i) {
    int e = tid + (i << 8);
    int r = e >> 3, dblk = e & 7;
    *(uint4*)(&Qs[r * 72 + dblk * 8]) = *(const uint4*)(q + r * 64 + dblk * 8);
    *(uint4*)(&Ks[r * 72 + dblk * 8]) = *(const uint4*)(k + r * 64 + dblk * 8);
    uint4 vv = *(const uint4*)(v + r * 64 + dblk * 8);
    const unsigned short* pv = (const unsigned short*)&vv;
#pragma unroll
    for (int j = 0; j < 8; ++j)
      VT[(dblk * 8 + j) * 72 + r] = pv[j];
  }
  __syncthreads();
  const int lane = tid & 63, wid = tid >> 6;
  const int quad = lane >> 4, l15 = lane & 15;
  const int qs = wid << 4;
  short8 aq0 = *(const short8*)(&Qs[(qs + l15) * 72 + quad * 8]);
  short8 aq1 = *(const short8*)(&Qs[(qs + l15) * 72 + 32 + quad * 8]);
  floatx4 s[4] = {};
#pragma unroll
  for (int ni = 0; ni < 4; ++ni) {
    short8 b0 = *(const short8*)(&Ks[(ni * 16 + l15) * 72 + quad * 8]);
    short8 b1 = *(const short8*)(&Ks[(ni * 16 + l15) * 72 + 32 + quad * 8]);
    s[ni] = MFMA16(aq0, b0, s[ni]);
    s[ni] = MFMA16(aq1, b1, s[ni]);
  }
#pragma unroll
  for (int r = 0; r < 4; ++r) {
    float e0 = s[0][r] * 0.125f, e1 = s[1][r] * 0.125f;
    float e2 = s[2][r] * 0.125f, e3 = s[3][r] * 0.125f;
    float m = fmaxf(fmaxf(e0, e1), fmaxf(e2, e3));
    m = fmaxf(m, __shfl_xor(m, 1));
    m = fmaxf(m, __shfl_xor(m, 2));
    m = fmaxf(m, __shfl_xor(m, 4));
    m = fmaxf(m, __shfl_xor(m, 8));
    float x0 = __expf(e0 - m), x1 = __expf(e1 - m);
    float x2 = __expf(e2 - m), x3 = __expf(e3 - m);
    float t = x0 + x1 + x2 + x3;
    t += __shfl_xor(t, 1); t += __shfl_xor(t, 2);
    t += __shfl_xor(t, 4); t += __shfl_xor(t, 8);
    float inv = __builtin_amdgcn_rcpf(t);
    int row = qs + (quad << 2) + r;
    Ps[row * 72 +      l15] = f2bf(x0 * inv);
    Ps[row * 72 + 16 + l15] = f2bf(x1 * inv);
    Ps[row * 72 + 32 + l15] = f2bf(x2 * inv);
    Ps[row * 72 + 48 + l15] = f2bf(x3 * inv);
  }
  __syncthreads();
  short8 ap0 = *(const short8*)(&Ps[(qs + l15) * 72 + quad * 8]);
  short8 ap1 = *(const short8*)(&Ps[(qs + l15) * 72 + 32 + quad * 8]);
  floatx4 o[4] = {};
#pragma unroll
  for (int ni = 0; ni < 4; ++ni) {
    short8 b0 = *(const short8*)(&VT[(ni * 16 + l15) * 72 + quad * 8]);
    short8 b1 = *(const short8*)(&VT[(ni * 16 + l15) * 72 + 32 + quad * 8]);
    o[ni] = MFMA16(ap0, b0, o[ni]);
    o[ni] = MFMA16(ap1, b1, o[ni]);
  }
  unsigned short* outp = Ob + base;
#pragma unroll
  for (int ni = 0; ni < 4; ++ni)
#pragma unroll
    for (int r = 0; r < 4; ++r)
      outp[(qs + (quad << 2) + r) * 64 + ni * 16 + l15] = f2bf(o[ni][r]);
}

// ---------------- out gemm: C_f32[512][512] += Ob * WoT^T, split-K 32 ------
__global__ __launch_bounds__(256) void gemm_out(const unsigned short* __restrict__ A,
                                                const unsigned short* __restrict__ BT,
                                                const float* __restrict__ bias,
                                                float* __restrict__ C) {
  __shared__ __align__(16) unsigned short As[128 * 64];
  __shared__ __align__(16) unsigned short Bs[128 * 64];
  const int tid = threadIdx.x;
  const int lane = tid & 63, wid = tid >> 6;
  const int quad = lane >> 4, l15 = lane & 15;
  const int wm = wid >> 1, wn = wid & 1;
  const int m0 = blockIdx.y * 128, n0 = blockIdx.x * 128;
  const int kbase = blockIdx.z * 1024;
  floatx4 acc[4][4] = {};
  for (int k0 = kbase; k0 < kbase + 1024; k0 += 64) {
    STAGE_TILE(A + (size_t)m0 * 32768 + k0, 32768, As);
    STAGE_TILE(BT + (size_t)n0 * 32768 + k0, 32768, Bs);
    __syncthreads();
#pragma unroll
    for (int ks = 0; ks < 2; ++ks) {
      short8 aF[4], bF[4];
#pragma unroll
      for (int mi = 0; mi < 4; ++mi) aF[mi] = FRAG(As, wm * 64 + mi * 16 + l15, ks);
#pragma unroll
      for (int ni = 0; ni < 4; ++ni) bF[ni] = FRAG(Bs, wn * 64 + ni * 16 + l15, ks);
#pragma unroll
      for (int mi = 0; mi < 4; ++mi)
#pragma unroll
        for (int ni = 0; ni < 4; ++ni)
          acc[mi][ni] = MFMA16(aF[mi], bF[ni], acc[mi][ni]);
    }
    __syncthreads();
  }
#pragma unroll
  for (int ni = 0; ni < 4; ++ni) {
    int col = n0 + wn * 64 + ni * 16 + l15;
    float bv = (blockIdx.z == 0) ? bias[col] : 0.0f;
#pragma unroll
    for (int mi = 0; mi < 4; ++mi) {
      int row = m0 + wm * 64 + mi * 16 + (quad << 2);
#pragma unroll
      for (int r = 0; r < 4; ++r)
        atomicAdd(&C[(size_t)(row + r) * 512 + col], acc[mi][ni][r] + bv);
    }
  }
}

extern "C" void kernel_launch(void* const* d_in, const int* in_sizes, int n_in,
                              void* d_out, int out_size, void* d_ws, size_t ws_size,
                              hipStream_t stream) {
  const float* x  = (const float*)d_in[0];
  const float* z  = (const float*)d_in[1];
  const float* Wq = (const float*)d_in[2];
  const float* bq = (const float*)d_in[3];
  const float* Wk = (const float*)d_in[4];
  const float* bk = (const float*)d_in[5];
  const float* Wv = (const float*)d_in[6];
  const float* bv = (const float*)d_in[7];
  const float* Wo = (const float*)d_in[8];
  const float* bo = (const float*)d_in[9];
  float* out = (float*)d_out;
  char* ws = (char*)d_ws;

  unsigned short* WqT = (unsigned short*)(ws + 0);
  unsigned short* WkT = (unsigned short*)(ws + 16777216);
  unsigned short* WvT = (unsigned short*)(ws + 50331648);
  unsigned short* Qb  = (unsigned short*)(ws + 83886080);
  unsigned short* Kb  = (unsigned short*)(ws + 117440512);
  unsigned short* Vb  = (unsigned short*)(ws + 150994944);
  unsigned short* Ob  = (unsigned short*)(ws + 0);          // over dead WqT/WkT
  unsigned short* WoT = (unsigned short*)(ws + 50331648);   // over dead WvT

  // d_out doubles as scratch for bf16 activations until the memset below.
  unsigned short* xb = (unsigned short*)d_out;                       // 512 KB
  unsigned short* zb = (unsigned short*)((char*)d_out + 524288);     // 256 KB

  convert_xz<<<dim3(192), 256, 0, stream>>>(x, z, xb, zb);
  transpose_qkv<<<dim3(512, 8, 3), 256, 0, stream>>>(Wq, Wk, Wv, WqT, WkT, WvT);

  gemm_qkv<<<dim3(256, 4, 3), 256, 0, stream>>>(xb, zb, WqT, WkT, WvT,
                                                bq, bk, bv, Qb, Kb, Vb);

  transpose_wo<<<dim3(8, 512), 256, 0, stream>>>(Wo, WoT);   // WvT now dead

  attn64<<<dim3(4096), 256, 0, stream>>>(Qb, Kb, Vb, Ob);    // Ob over dead WqT/WkT

  hipMemsetAsync(d_out, 0, (size_t)out_size * sizeof(float), stream);
  gemm_out<<<dim3(4, 4, 32), 256, 0, stream>>>(Ob, WoT, bo, out);
}

// Round 3
// 384.349 us; speedup vs baseline: 1.1696x; 1.0326x over previous
//
#include <hip/hip_runtime.h>
#include <stdint.h>

// ---------------------------------------------------------------------------
// MultiHeadAttnCoupling: B=4 N=128 -> BN=512 rows
//   Q = z(512x256) @ Wq(256x32768) + bq
//   K = x(512x512) @ Wk(512x32768) + bk ; V likewise
//   per (bn, h in 0..7): S = Q64x64 K^T /8 ; P=softmax(S); O = P V
//   out = O(512x32768) @ Wo(32768x512) + bo   (fp32 out)
//
// ws layout (bytes), peak 184,549,376:
//   WqT @ 0          (16MB)  } dead after gemm_qkv -> Ob @ 0 (32MB)
//   WkT @ 16,777,216 (32MB)  }
//   WvT @ 50,331,648 (32MB)    dead after gemm_qkv -> WoT @ same (32MB)
//   Qb  @ 83,886,080  Kb @ 117,440,512  Vb @ 150,994,944 (bf16, 32MB each)
// d_out (1MB) doubles as scratch for xb (512KB) + zb (256KB) until the
// memset right before gemm_out.
// ---------------------------------------------------------------------------

typedef __attribute__((ext_vector_type(8))) short short8;
typedef __attribute__((ext_vector_type(4))) float floatx4;

__device__ __forceinline__ unsigned short f2bf(float f) {
  union { float f; unsigned int u; } v; v.f = f;
  unsigned int u = v.u + 0x7FFFu + ((v.u >> 16) & 1u);   // round-to-nearest-even
  return (unsigned short)(u >> 16);
}

#define MFMA16(a, b, c) __builtin_amdgcn_mfma_f32_16x16x32_bf16((a), (b), (c), 0, 0, 0)

// Stage a 128-row x 64-k bf16 tile into LDS via global_load_lds (16B/lane).
// XOR swizzle: logical k-chunk c (16B granule) of row r stored at slot c^(r&7).
#define STAGE_TILE(SRC, LD, LDSARR)                                            \
  do {                                                                         \
    _Pragma("unroll") for (int i_ = 0; i_ < 4; ++i_) {                         \
      int e_ = tid + (i_ << 8);                                                \
      int r_ = e_ >> 3;                                                        \
      int c_ = (e_ & 7) ^ (r_ & 7);                                            \
      __builtin_amdgcn_global_load_lds(                                        \
          (const __attribute__((address_space(1))) unsigned int*)((SRC) +      \
              (size_t)r_ * (LD) + (c_ << 3)),                                  \
          (__attribute__((address_space(3))) unsigned int*)(&(LDSARR)[e_ << 3]),\
          16, 0, 0);                                                           \
    }                                                                          \
  } while (0)

// Fragment read: row in [0,128), KS in {0,1}; logical chunk = KS*4+quad,
// stored at (KS*4+quad)^(row&7). Element offset = row*64 + chunk*8.
#define FRAG(LDSARR, ROW, KS)                                                  \
  (*(const short8*)(&(LDSARR)[(((ROW) << 6)) +                                 \
      ((((((KS) << 2) + quad)) ^ ((ROW) & 7)) << 3)]))

// ---------------- conflict-free transpose: W[K][N] f32 -> WT[N][K] bf16 ----
// 3-phase per 64x64 tile:
//   P1: coalesced f32x4 rows -> S[64][72] fp32 (b128, uniform bank slots)
//   P2: column reads S[k*72+n] (n=lane: 2-way, free) -> f2bf pack ->
//       T[n][72] bf16 rows via b128 (4n mod 32: uniform)
//   P3: b128 row reads of T -> 16B/lane coalesced global store
__device__ __forceinline__ void transpose_body(const float* __restrict__ W,
                                               unsigned short* __restrict__ WT,
                                               int Kd, int Nd) {
  __shared__ __align__(16) float S[64 * 72];
  __shared__ __align__(16) unsigned short T[64 * 72];
  const int tid = threadIdx.x;
  const int n0 = blockIdx.x * 64, k0 = blockIdx.y * 64;
#pragma unroll
  for (int i = 0; i < 4; ++i) {
    int e = tid + (i << 8);            // [0,1024): 64 k-rows x 16 float4
    int r = e >> 4, c = (e & 15) << 2;
    float4 w = *(const float4*)(W + (size_t)(k0 + r) * Nd + n0 + c);
    *(float4*)(&S[r * 72 + c]) = w;    // bytes r*288 + c*4, 16B aligned
  }
  __syncthreads();
  {
    const int n = tid & 63, kh = tid >> 6;   // kh wave-uniform 0..3
    float v[16];
#pragma unroll
    for (int j = 0; j < 16; ++j) v[j] = S[(kh * 16 + j) * 72 + n];
    uint4 p0, p1;
    p0.x = f2bf(v[0])  | ((unsigned)f2bf(v[1])  << 16);
    p0.y = f2bf(v[2])  | ((unsigned)f2bf(v[3])  << 16);
    p0.z = f2bf(v[4])  | ((unsigned)f2bf(v[5])  << 16);
    p0.w = f2bf(v[6])  | ((unsigned)f2bf(v[7])  << 16);
    p1.x = f2bf(v[8])  | ((unsigned)f2bf(v[9])  << 16);
    p1.y = f2bf(v[10]) | ((unsigned)f2bf(v[11]) << 16);
    p1.z = f2bf(v[12]) | ((unsigned)f2bf(v[13]) << 16);
    p1.w = f2bf(v[14]) | ((unsigned)f2bf(v[15]) << 16);
    *(uint4*)(&T[n * 72 + kh * 16])     = p0;  // bytes n*144 + kh*32, 16B ok
    *(uint4*)(&T[n * 72 + kh * 16 + 8]) = p1;
  }
  __syncthreads();
#pragma unroll
  for (int i = 0; i < 2; ++i) {
    int e = tid + (i << 8);            // [0,512): 64 n-rows x 8 x 16B
    int n = e >> 3, kc = e & 7;
    uint4 vv = *(const uint4*)(&T[n * 72 + kc * 8]);
    *(uint4*)(WT + (size_t)(n0 + n) * Kd + k0 + kc * 8) = vv;
  }
}

// z=0..2: Wq/Wk/Wv transpose; z=3: x,z fp32->bf16 convert (folded in)
__global__ __launch_bounds__(256) void transpose_qkv(const float* __restrict__ Wq,
                                                     const float* __restrict__ Wk,
                                                     const float* __restrict__ Wv,
                                                     unsigned short* __restrict__ WqT,
                                                     unsigned short* __restrict__ WkT,
                                                     unsigned short* __restrict__ WvT,
                                                     const float* __restrict__ x,
                                                     const float* __restrict__ z,
                                                     unsigned short* __restrict__ xb,
                                                     unsigned short* __restrict__ zb) {
  const int zsel = blockIdx.z;
  if (zsel == 0) {
    if (blockIdx.y >= 4) return;                 // Wq: K=256 -> only 4 k-blocks
    transpose_body(Wq, WqT, 256, 32768);
  } else if (zsel == 1) {
    transpose_body(Wk, WkT, 512, 32768);
  } else if (zsel == 2) {
    transpose_body(Wv, WvT, 512, 32768);
  } else {
    if (blockIdx.y != 0 || blockIdx.x >= 192) return;
    int idx = (blockIdx.x * 256 + threadIdx.x) * 8;   // 192*2048 = 393216
    const float* src;
    unsigned short* dst;
    if (idx < 262144) { src = x + idx; dst = xb + idx; }
    else              { src = z + (idx - 262144); dst = zb + (idx - 262144); }
    float4 f0 = *(const float4*)src;
    float4 f1 = *(const float4*)(src + 4);
    uint4 p;
    p.x = f2bf(f0.x) | ((unsigned)f2bf(f0.y) << 16);
    p.y = f2bf(f0.z) | ((unsigned)f2bf(f0.w) << 16);
    p.z = f2bf(f1.x) | ((unsigned)f2bf(f1.y) << 16);
    p.w = f2bf(f1.z) | ((unsigned)f2bf(f1.w) << 16);
    *(uint4*)dst = p;
  }
}

__global__ __launch_bounds__(256) void transpose_wo(const float* __restrict__ W,
                                                    unsigned short* __restrict__ WT) {
  transpose_body(W, WT, 32768, 512);
}

// ---------------- fused QKV gemm: C_bf16 = A_bf16 * BT^T + bias ------------
__global__ __launch_bounds__(256) void gemm_qkv(const unsigned short* __restrict__ xb,
                                                const unsigned short* __restrict__ zb,
                                                const unsigned short* __restrict__ WqT,
                                                const unsigned short* __restrict__ WkT,
                                                const unsigned short* __restrict__ WvT,
                                                const float* __restrict__ bq,
                                                const float* __restrict__ bk,
                                                const float* __restrict__ bv,
                                                unsigned short* __restrict__ Qb,
                                                unsigned short* __restrict__ Kb,
                                                unsigned short* __restrict__ Vb) {
  __shared__ __align__(16) unsigned short As[128 * 64];
  __shared__ __align__(16) unsigned short Bs[128 * 64];
  const int tid = threadIdx.x;
  const int zsel = blockIdx.z;
  const unsigned short* A;
  const unsigned short* BT;
  const float* bias;
  unsigned short* C;
  int Ka;
  if (zsel == 0)      { A = zb; BT = WqT; bias = bq; C = Qb; Ka = 256; }
  else if (zsel == 1) { A = xb; BT = WkT; bias = bk; C = Kb; Ka = 512; }
  else                { A = xb; BT = WvT; bias = bv; C = Vb; Ka = 512; }
  const int lane = tid & 63, wid = tid >> 6;
  const int quad = lane >> 4, l15 = lane & 15;
  const int wm = wid >> 1, wn = wid & 1;
  const int m0 = blockIdx.y * 128, n0 = blockIdx.x * 128;
  floatx4 acc[4][4] = {};
  for (int k0 = 0; k0 < Ka; k0 += 64) {
    STAGE_TILE(A + (size_t)m0 * Ka + k0, Ka, As);
    STAGE_TILE(BT + (size_t)n0 * Ka + k0, Ka, Bs);
    __syncthreads();
#pragma unroll
    for (int ks = 0; ks < 2; ++ks) {
      short8 aF[4], bF[4];
#pragma unroll
      for (int mi = 0; mi < 4; ++mi) aF[mi] = FRAG(As, wm * 64 + mi * 16 + l15, ks);
#pragma unroll
      for (int ni = 0; ni < 4; ++ni) bF[ni] = FRAG(Bs, wn * 64 + ni * 16 + l15, ks);
#pragma unroll
      for (int mi = 0; mi < 4; ++mi)
#pragma unroll
        for (int ni = 0; ni < 4; ++ni)
          acc[mi][ni] = MFMA16(aF[mi], bF[ni], acc[mi][ni]);
    }
    __syncthreads();
  }
#pragma unroll
  for (int ni = 0; ni < 4; ++ni) {
    int col = n0 + wn * 64 + ni * 16 + l15;
    float bv2 = bias[col];
#pragma unroll
    for (int mi = 0; mi < 4; ++mi) {
      int row = m0 + wm * 64 + mi * 16 + (quad << 2);
#pragma unroll
      for (int r = 0; r < 4; ++r)
        C[(size_t)(row + r) * 32768 + col] = f2bf(acc[mi][ni][r] + bv2);
    }
  }
}

// ---------------- attention: one block per (bn, h), 64x64 tiles ------------
__global__ __launch_bounds__(256) void attn64(const unsigned short* __restrict__ Qb,
                                              const unsigned short* __restrict__ Kb,
                                              const unsigned short* __restrict__ Vb,
                                              unsigned short* __restrict__ Ob) {
  __shared__ __align__(16) unsigned short Qs[64 * 72];
  __shared__ __align__(16) unsigned short Ks[64 * 72];
  __shared__ __align__(16) unsigned short VT[64 * 72];
  __shared__ __align__(16) unsigned short Ps[64 * 72];
  const int tid = threadIdx.x;
  const int bn = blockIdx.x >> 3, h = blockIdx.x & 7;
  const size_t base = (size_t)bn * 32768 + (size_t)h * 4096;
  const unsigned short* q = Qb + base;
  const unsigned short* k = Kb + base;
  const unsigned short* v = Vb + base;
#pragma unroll
  for (int i = 0; i < 2; ++i) {
    int e = tid + (i << 8);
    int r = e >> 3, dblk = e & 7;
    *(uint4*)(&Qs[r * 72 + dblk * 8]) = *(const uint4*)(q + r * 64 + dblk * 8);
    *(uint4*)(&Ks[r * 72 + dblk * 8]) = *(const uint4*)(k + r * 64 + dblk * 8);
    uint4 vv = *(const uint4*)(v + r * 64 + dblk * 8);
    const unsigned short* pv = (const unsigned short*)&vv;
#pragma unroll
    for (int j = 0; j < 8; ++j)
      VT[(dblk * 8 + j) * 72 + r] = pv[j];
  }
  __syncthreads();
  const int lane = tid & 63, wid = tid >> 6;
  const int quad = lane >> 4, l15 = lane & 15;
  const int qs = wid << 4;
  short8 aq0 = *(const short8*)(&Qs[(qs + l15) * 72 + quad * 8]);
  short8 aq1 = *(const short8*)(&Qs[(qs + l15) * 72 + 32 + quad * 8]);
  floatx4 s[4] = {};
#pragma unroll
  for (int ni = 0; ni < 4; ++ni) {
    short8 b0 = *(const short8*)(&Ks[(ni * 16 + l15) * 72 + quad * 8]);
    short8 b1 = *(const short8*)(&Ks[(ni * 16 + l15) * 72 + 32 + quad * 8]);
    s[ni] = MFMA16(aq0, b0, s[ni]);
    s[ni] = MFMA16(aq1, b1, s[ni]);
  }
#pragma unroll
  for (int r = 0; r < 4; ++r) {
    float e0 = s[0][r] * 0.125f, e1 = s[1][r] * 0.125f;
    float e2 = s[2][r] * 0.125f, e3 = s[3][r] * 0.125f;
    float m = fmaxf(fmaxf(e0, e1), fmaxf(e2, e3));
    m = fmaxf(m, __shfl_xor(m, 1));
    m = fmaxf(m, __shfl_xor(m, 2));
    m = fmaxf(m, __shfl_xor(m, 4));
    m = fmaxf(m, __shfl_xor(m, 8));
    float x0 = __expf(e0 - m), x1 = __expf(e1 - m);
    float x2 = __expf(e2 - m), x3 = __expf(e3 - m);
    float t = x0 + x1 + x2 + x3;
    t += __shfl_xor(t, 1); t += __shfl_xor(t, 2);
    t += __shfl_xor(t, 4); t += __shfl_xor(t, 8);
    float inv = __builtin_amdgcn_rcpf(t);
    int row = qs + (quad << 2) + r;
    Ps[row * 72 +      l15] = f2bf(x0 * inv);
    Ps[row * 72 + 16 + l15] = f2bf(x1 * inv);
    Ps[row * 72 + 32 + l15] = f2bf(x2 * inv);
    Ps[row * 72 + 48 + l15] = f2bf(x3 * inv);
  }
  __syncthreads();
  short8 ap0 = *(const short8*)(&Ps[(qs + l15) * 72 + quad * 8]);
  short8 ap1 = *(const short8*)(&Ps[(qs + l15) * 72 + 32 + quad * 8]);
  floatx4 o[4] = {};
#pragma unroll
  for (int ni = 0; ni < 4; ++ni) {
    short8 b0 = *(const short8*)(&VT[(ni * 16 + l15) * 72 + quad * 8]);
    short8 b1 = *(const short8*)(&VT[(ni * 16 + l15) * 72 + 32 + quad * 8]);
    o[ni] = MFMA16(ap0, b0, o[ni]);
    o[ni] = MFMA16(ap1, b1, o[ni]);
  }
  unsigned short* outp = Ob + base;
#pragma unroll
  for (int ni = 0; ni < 4; ++ni)
#pragma unroll
    for (int r = 0; r < 4; ++r)
      outp[(qs + (quad << 2) + r) * 64 + ni * 16 + l15] = f2bf(o[ni][r]);
}

// ---------------- out gemm: C_f32[512][512] += Ob * WoT^T, split-K 32 ------
__global__ __launch_bounds__(256) void gemm_out(const unsigned short* __restrict__ A,
                                                const unsigned short* __restrict__ BT,
                                                const float* __restrict__ bias,
                                                float* __restrict__ C) {
  __shared__ __align__(16) unsigned short As[128 * 64];
  __shared__ __align__(16) unsigned short Bs[128 * 64];
  const int tid = threadIdx.x;
  const int lane = tid & 63, wid = tid >> 6;
  const int quad = lane >> 4, l15 = lane & 15;
  const int wm = wid >> 1, wn = wid & 1;
  const int m0 = blockIdx.y * 128, n0 = blockIdx.x * 128;
  const int kbase = blockIdx.z * 1024;
  floatx4 acc[4][4] = {};
  for (int k0 = kbase; k0 < kbase + 1024; k0 += 64) {
    STAGE_TILE(A + (size_t)m0 * 32768 + k0, 32768, As);
    STAGE_TILE(BT + (size_t)n0 * 32768 + k0, 32768, Bs);
    __syncthreads();
#pragma unroll
    for (int ks = 0; ks < 2; ++ks) {
      short8 aF[4], bF[4];
#pragma unroll
      for (int mi = 0; mi < 4; ++mi) aF[mi] = FRAG(As, wm * 64 + mi * 16 + l15, ks);
#pragma unroll
      for (int ni = 0; ni < 4; ++ni) bF[ni] = FRAG(Bs, wn * 64 + ni * 16 + l15, ks);
#pragma unroll
      for (int mi = 0; mi < 4; ++mi)
#pragma unroll
        for (int ni = 0; ni < 4; ++ni)
          acc[mi][ni] = MFMA16(aF[mi], bF[ni], acc[mi][ni]);
    }
    __syncthreads();
  }
#pragma unroll
  for (int ni = 0; ni < 4; ++ni) {
    int col = n0 + wn * 64 + ni * 16 + l15;
    float bv = (blockIdx.z == 0) ? bias[col] : 0.0f;
#pragma unroll
    for (int mi = 0; mi < 4; ++mi) {
      int row = m0 + wm * 64 + mi * 16 + (quad << 2);
#pragma unroll
      for (int r = 0; r < 4; ++r)
        atomicAdd(&C[(size_t)(row + r) * 512 + col], acc[mi][ni][r] + bv);
    }
  }
}

extern "C" void kernel_launch(void* const* d_in, const int* in_sizes, int n_in,
                              void* d_out, int out_size, void* d_ws, size_t ws_size,
                              hipStream_t stream) {
  const float* x  = (const float*)d_in[0];
  const float* z  = (const float*)d_in[1];
  const float* Wq = (const float*)d_in[2];
  const float* bq = (const float*)d_in[3];
  const float* Wk = (const float*)d_in[4];
  const float* bk = (const float*)d_in[5];
  const float* Wv = (const float*)d_in[6];
  const float* bv = (const float*)d_in[7];
  const float* Wo = (const float*)d_in[8];
  const float* bo = (const float*)d_in[9];
  float* out = (float*)d_out;
  char* ws = (char*)d_ws;

  unsigned short* WqT = (unsigned short*)(ws + 0);
  unsigned short* WkT = (unsigned short*)(ws + 16777216);
  unsigned short* WvT = (unsigned short*)(ws + 50331648);
  unsigned short* Qb  = (unsigned short*)(ws + 83886080);
  unsigned short* Kb  = (unsigned short*)(ws + 117440512);
  unsigned short* Vb  = (unsigned short*)(ws + 150994944);
  unsigned short* Ob  = (unsigned short*)(ws + 0);          // over dead WqT/WkT
  unsigned short* WoT = (unsigned short*)(ws + 50331648);   // over dead WvT

  // d_out doubles as scratch for bf16 activations until the memset below.
  unsigned short* xb = (unsigned short*)d_out;                       // 512 KB
  unsigned short* zb = (unsigned short*)((char*)d_out + 524288);     // 256 KB

  transpose_qkv<<<dim3(512, 8, 4), 256, 0, stream>>>(Wq, Wk, Wv, WqT, WkT, WvT,
                                                     x, z, xb, zb);

  gemm_qkv<<<dim3(256, 4, 3), 256, 0, stream>>>(xb, zb, WqT, WkT, WvT,
                                                bq, bk, bv, Qb, Kb, Vb);

  transpose_wo<<<dim3(8, 512), 256, 0, stream>>>(Wo, WoT);   // WvT now dead

  attn64<<<dim3(4096), 256, 0, stream>>>(Qb, Kb, Vb, Ob);    // Ob over dead WqT/WkT

  hipMemsetAsync(d_out, 0, (size_t)out_size * sizeof(float), stream);
  gemm_out<<<dim3(4, 4, 32), 256, 0, stream>>>(Ob, WoT, bo, out);
}